// Round 11
// baseline (186.996 us; speedup 1.0000x reference)
//
#include <hip/hip_runtime.h>
#include <cstdint>
#include <math.h>

typedef __attribute__((ext_vector_type(8))) short short8;
typedef __attribute__((ext_vector_type(4))) short shortx4;
typedef __attribute__((ext_vector_type(4))) float floatx4;
typedef __attribute__((ext_vector_type(16))) float floatx16;
typedef __attribute__((ext_vector_type(2))) unsigned uint2v;

#define D_MODEL 1024
#define NHEAD   16
#define HDIM    64
#define BATCH   2
#define SEQ     2048
#define MTOT    (BATCH*SEQ)   /* 4096 */

#if __has_builtin(__builtin_amdgcn_exp2f)
#define EXP2(x) __builtin_amdgcn_exp2f(x)
#else
#define EXP2(x) exp2f(x)
#endif

// round-to-nearest-even f32 -> bf16 (bits in a short)
__device__ __forceinline__ short f2bf(float f) {
    union { float f; uint32_t u; } v; v.f = f;
    uint32_t u = v.u;
    uint32_t r = (u + 0x7fffu + ((u >> 16) & 1u)) >> 16;
    return (short)(uint16_t)r;
}

// pack two f32 -> [bf16(lo) | bf16(hi)<<16] in ONE VALU op (T12 recipe; RNE rounding)
__device__ __forceinline__ unsigned pkcvt(float lo, float hi) {
    unsigned r;
    asm("v_cvt_pk_bf16_f32 %0, %1, %2" : "=v"(r) : "v"(lo), "v"(hi));
    return r;
}

// async global->LDS, 16B per lane. LDS dest must be wave-uniform base + lane*16.
__device__ __forceinline__ void async16(const short* g, short* l) {
    __builtin_amdgcn_global_load_lds((__attribute__((address_space(1))) void*)g,
                                     (__attribute__((address_space(3))) void*)l,
                                     16, 0, 0);
}

// ---------------------------------------------------------------- merged cast
__global__ __launch_bounds__(256) void cast_all_kernel(
    const float* __restrict__ x,  const float* __restrict__ Wq, const float* __restrict__ Wk,
    const float* __restrict__ Wv, const float* __restrict__ Wo,
    short* __restrict__ xb, short* __restrict__ wqb, short* __restrict__ wkb,
    short* __restrict__ wvb, short* __restrict__ wob)
{
    const int i = blockIdx.x * 256 + threadIdx.x;   // 8-elem group index
    const float* src; short* dst; int off;
    if (i < 524288) { src = x; dst = xb; off = i; }
    else {
        const int j = i - 524288;
        const int seg = j >> 17, o = j & 131071;
        src = (seg == 0) ? Wq : (seg == 1) ? Wk : (seg == 2) ? Wv : Wo;
        dst = (seg == 0) ? wqb : (seg == 1) ? wkb : (seg == 2) ? wvb : wob;
        off = o;
    }
    const floatx4* p = (const floatx4*)(src + (size_t)off * 8);
    floatx4 a = p[0], b = p[1];
    short8 r;
    r[0]=f2bf(a[0]); r[1]=f2bf(a[1]); r[2]=f2bf(a[2]); r[3]=f2bf(a[3]);
    r[4]=f2bf(b[0]); r[5]=f2bf(b[1]); r[6]=f2bf(b[2]); r[7]=f2bf(b[3]);
    *(short8*)(dst + (size_t)off * 8) = r;
}

// ---------------------------------------------------------------- QKV GEMM
__global__ __launch_bounds__(256, 3) void qkv_gemm_kernel(
    const short* __restrict__ Xb,
    const short* __restrict__ Wqb, const short* __restrict__ Wkb, const short* __restrict__ Wvb,
    const float* __restrict__ bq, const float* __restrict__ bk, const float* __restrict__ bv,
    short* __restrict__ Qo, short* __restrict__ Ko, short* __restrict__ Vo)
{
    const int mode = blockIdx.z;
    const short* W    = (mode == 0) ? Wqb : (mode == 1) ? Wkb : Wvb;
    const float* bias = (mode == 0) ? bq  : (mode == 1) ? bk  : bv;

    const int m_t = blockIdx.y * 128;
    const int n_t = blockIdx.x * 128;
    const int tid = threadIdx.x;
    const int lane = tid & 63, laneM = lane & 15, quad = lane >> 4;
    const int wave = tid >> 6;
    const int wm = (wave >> 1) * 64, wn = (wave & 1) * 64;

    __shared__ short la[2][128][4][8];   // [buf][row][slot][8]
    __shared__ short lb[2][128][4][8];

    floatx4 acc[4][4];
#pragma unroll
    for (int mb = 0; mb < 4; mb++)
#pragma unroll
        for (int nb = 0; nb < 4; nb++) acc[mb][nb] = (floatx4){0.f,0.f,0.f,0.f};

#define QSTAGE(bf, kk)                                                                  \
    {                                                                                   \
        int c = tid;                                                                    \
        async16(Xb + (size_t)(m_t + (c >> 2)) * D_MODEL + (kk) + ((((c & 3) ^ ((c >> 3) & 3))) * 8), \
                &la[bf][0][0][0] + c * 8);                                              \
        c = tid + 256;                                                                  \
        async16(Xb + (size_t)(m_t + (c >> 2)) * D_MODEL + (kk) + ((((c & 3) ^ ((c >> 3) & 3))) * 8), \
                &la[bf][0][0][0] + c * 8);                                              \
        c = tid;                                                                        \
        async16(W  + (size_t)(n_t + (c >> 2)) * D_MODEL + (kk) + ((((c & 3) ^ ((c >> 3) & 3))) * 8), \
                &lb[bf][0][0][0] + c * 8);                                              \
        c = tid + 256;                                                                  \
        async16(W  + (size_t)(n_t + (c >> 2)) * D_MODEL + (kk) + ((((c & 3) ^ ((c >> 3) & 3))) * 8), \
                &lb[bf][0][0][0] + c * 8);                                              \
    }

    QSTAGE(0, 0)

    const int swz = (laneM >> 1) & 3;
    for (int it = 0; it < 32; ++it) {
        const int bf = it & 1;
        __syncthreads();                       // buf[it] ready

        short8 af[4], bfv[4];
#pragma unroll
        for (int mb = 0; mb < 4; mb++) af[mb]  = *(const short8*)&la[bf][wm + mb*16 + laneM][quad ^ swz][0];
#pragma unroll
        for (int nb = 0; nb < 4; nb++) bfv[nb] = *(const short8*)&lb[bf][wn + nb*16 + laneM][quad ^ swz][0];

        if (it < 31) QSTAGE(bf ^ 1, (it + 1) * 32)

#pragma unroll
        for (int mb = 0; mb < 4; mb++)
#pragma unroll
            for (int nb = 0; nb < 4; nb++)
                acc[mb][nb] = __builtin_amdgcn_mfma_f32_16x16x32_bf16(af[mb], bfv[nb], acc[mb][nb], 0, 0, 0);
    }
#undef QSTAGE

    if (mode == 2) {
        // V: store transposed [bh][d][seq], shortx4 along seq
#pragma unroll
        for (int nb = 0; nb < 4; nb++) {
            const int col = n_t + wn + nb*16 + laneM;
            const float bb = bias[col];
            const int h = col >> 6, d = col & 63;
#pragma unroll
            for (int mb = 0; mb < 4; mb++) {
                const int row0 = m_t + wm + mb*16 + quad*4;
                const int bi = row0 >> 11, seq0 = row0 & 2047;
                shortx4 sv;
#pragma unroll
                for (int r = 0; r < 4; r++) sv[r] = f2bf(acc[mb][nb][r] + bb);
                *(shortx4*)(Vo + ((size_t)(bi*NHEAD + h) * HDIM + d) * SEQ + seq0) = sv;
            }
        }
    } else {
        short* out = (mode == 0) ? Qo : Ko;
#pragma unroll
        for (int nb = 0; nb < 4; nb++) {
            const int col = n_t + wn + nb*16 + laneM;
            const float bb = bias[col];
            const int h = col >> 6, d = col & 63;
#pragma unroll
            for (int mb = 0; mb < 4; mb++) {
                const int row0 = m_t + wm + mb*16 + quad*4;
#pragma unroll
                for (int r = 0; r < 4; r++) {
                    float v = acc[mb][nb][r] + bb;
                    v = (mode == 0) ? (2.0f*v - 1.0f) * 0.18033688011112042f  // 0.125*log2(e)
                                    : (2.0f*v - 1.0f);
                    const int m = row0 + r;
                    const int bi = m >> 11, seq = m & 2047;
                    out[((size_t)(bi*NHEAD + h) * SEQ + seq) * HDIM + d] = f2bf(v);
                }
            }
        }
    }
}

// ---------------------------------------------------------------- output GEMM
// R4-green 128x64 tile (512 blocks = 2 blocks/CU).
__global__ __launch_bounds__(256, 3) void out_gemm_kernel(
    const short* __restrict__ Ab, const short* __restrict__ Wb,
    const float* __restrict__ bias, float* __restrict__ out)
{
    const int m_t = blockIdx.y * 128;
    const int n_t = blockIdx.x * 64;
    const int tid = threadIdx.x;
    const int lane = tid & 63, laneM = lane & 15, quad = lane >> 4;
    const int wave = tid >> 6;
    const int wm = (wave >> 1) * 64, wn = (wave & 1) * 32;

    __shared__ short la[2][128][4][8];
    __shared__ short lb[2][64][4][8];

    floatx4 acc[4][2];
#pragma unroll
    for (int mb = 0; mb < 4; mb++)
#pragma unroll
        for (int nb = 0; nb < 2; nb++) acc[mb][nb] = (floatx4){0.f,0.f,0.f,0.f};

#define OSTAGE(bf, kk)                                                                  \
    {                                                                                   \
        int c = tid;                                                                    \
        async16(Ab + (size_t)(m_t + (c >> 2)) * D_MODEL + (kk) + ((((c & 3) ^ ((c >> 3) & 3))) * 8), \
                &la[bf][0][0][0] + c * 8);                                              \
        c = tid + 256;                                                                  \
        async16(Ab + (size_t)(m_t + (c >> 2)) * D_MODEL + (kk) + ((((c & 3) ^ ((c >> 3) & 3))) * 8), \
                &la[bf][0][0][0] + c * 8);                                              \
        c = tid;                                                                        \
        async16(Wb + (size_t)(n_t + (c >> 2)) * D_MODEL + (kk) + ((((c & 3) ^ ((c >> 3) & 3))) * 8), \
                &lb[bf][0][0][0] + c * 8);                                              \
    }

    OSTAGE(0, 0)

    const int swz = (laneM >> 1) & 3;
    for (int it = 0; it < 32; ++it) {
        const int bf = it & 1;
        __syncthreads();

        short8 af[4], bfv[2];
#pragma unroll
        for (int mb = 0; mb < 4; mb++) af[mb]  = *(const short8*)&la[bf][wm + mb*16 + laneM][quad ^ swz][0];
#pragma unroll
        for (int nb = 0; nb < 2; nb++) bfv[nb] = *(const short8*)&lb[bf][wn + nb*16 + laneM][quad ^ swz][0];

        if (it < 31) OSTAGE(bf ^ 1, (it + 1) * 32)

#pragma unroll
        for (int mb = 0; mb < 4; mb++)
#pragma unroll
            for (int nb = 0; nb < 2; nb++)
                acc[mb][nb] = __builtin_amdgcn_mfma_f32_16x16x32_bf16(af[mb], bfv[nb], acc[mb][nb], 0, 0, 0);
    }
#undef OSTAGE

#pragma unroll
    for (int nb = 0; nb < 2; nb++) {
        const int col = n_t + wn + nb*16 + laneM;
        const float bb = bias[col];
#pragma unroll
        for (int mb = 0; mb < 4; mb++) {
            const int row0 = m_t + wm + mb*16 + quad*4;
#pragma unroll
            for (int r = 0; r < 4; r++)
                out[(size_t)(row0 + r) * D_MODEL + col] = acc[mb][nb][r] + bb;
        }
    }
}

// ---------------------------------------------------------------- flash attention
// R10-green structure (coalesced staging + swizzled LDS). THIS ROUND: fix the
// 4-way bank conflict R10's profile exposed (SQ_LDS_BANK_CONFLICT = 2^22 =
// exactly 4 cyc per ds_read_b128). Root cause: g(row)=row&7 uses only 3 row
// bits, so lanes {l, l+8, l+16, l+24} (same row&7, same doct) hit the same 16B
// bank group. Fix: g(row) = (row ^ (row>>3)) & 7 — folds row bits 3-4 in, so
// rows {r,r+8,r+16,r+24} map to 4 DISTINCT groups; every aligned 8-lane subset
// covers all 8 groups (0-conflict), 16-lane = 2-way (free, m136). Applied to
// BOTH staging source octet and read octet (involution; rule #21). Coalescing
// preserved (soct is a permutation within each 128B row).
__global__ __launch_bounds__(512, 4) void attn_kernel(const short* __restrict__ Qb,
                                                      const short* __restrict__ Kb,
                                                      const short* __restrict__ Vt,
                                                      short* __restrict__ Ob)
{
    const int bh = blockIdx.x & 31;
    const int qi = blockIdx.x >> 5;
    const int q0 = qi * 128;
    const int po = (qi & 3) * 4;                // phase stagger
    const int tid = threadIdx.x;
    const int wave = tid >> 6, lane = tid & 63;
    const int l31 = lane & 31;
    const bool hi = (lane >> 5) != 0;
    const int qg = wave & 3, par = wave >> 2;

    // K tile: [par][slot][key 64][d-octet 8][8]  (row-major key x d, swizzled oct)
    // V tile: [par][slot][d 64][key-octet 8][8]  (row-major d x key, swizzled koct)
    __shared__ short ktl[2][2][64][8][8];   // 32 KB
    __shared__ short vtl[2][2][64][8][8];   // 32 KB

    const short* Kbase = Kb + (size_t)bh * SEQ * HDIM;
    const short* Vbase = Vt + (size_t)bh * HDIM * SEQ;

    // Q fragments (MFMA B operand: B[k=d][n=q], lane n = q)
    const short* Qp = Qb + ((size_t)bh * SEQ + q0 + qg*32 + l31) * HDIM + (hi ? 8 : 0);
    short8 qf[4];
#pragma unroll
    for (int ks = 0; ks < 4; ks++) qf[ks] = *(const short8*)(Qp + ks*16);

    floatx16 o0, o1;
#pragma unroll
    for (int r = 0; r < 16; r++) { o0[r] = 0.f; o1[r] = 0.f; }
    float rsum = 0.f;

    // bank-spread swizzle for this thread's fragment rows: g(row)=(row^(row>>3))&7
    const int g0 = (l31 ^ (l31 >> 3)) & 7;   // rows l31      (a0 / v0)
    const int g1 = g0 ^ 4;                   // rows 32+l31   (a1 / v1): g(32+r)=g(r)^4

    // Coalesced stage: c = tid; row = c>>3, oct = c&7; source octet
    // soct = oct ^ g(row) (inverse swizzle on the global address).
#define STAGE(slot, kk)                                                                   \
    {                                                                                     \
        const int c = tid;                                                                \
        const int row_ = c >> 3;                                                          \
        const int soct_ = (c & 7) ^ ((row_ ^ (row_ >> 3)) & 7);                           \
        async16(Kbase + (size_t)((kk) + row_) * HDIM + soct_ * 8,                         \
                &ktl[0][slot][0][0][0] + c * 8);                                          \
        async16(Kbase + (size_t)((kk) + 64 + row_) * HDIM + soct_ * 8,                    \
                &ktl[1][slot][0][0][0] + c * 8);                                          \
        async16(Vbase + (size_t)row_ * SEQ + (kk) + soct_ * 8,                            \
                &vtl[0][slot][0][0][0] + c * 8);                                          \
        async16(Vbase + (size_t)row_ * SEQ + (kk) + 64 + soct_ * 8,                       \
                &vtl[1][slot][0][0][0] + c * 8);                                          \
    }

    STAGE(0, po * 128)

    for (int i = 0; i < 16; ++i) {
        const int slot = i & 1;
        __syncthreads();                        // both parity tiles of phase i ready
        if (i < 15) STAGE(slot ^ 1, (((i + 1 + po) & 15)) * 128)

        // S^T: D[m=key][n=q]   (swizzled read: oct = doct ^ g(row))
        floatx16 s0, s1;
#pragma unroll
        for (int r = 0; r < 16; r++) { s0[r] = 0.f; s1[r] = 0.f; }
        __builtin_amdgcn_s_setprio(1);
#pragma unroll
        for (int ks = 0; ks < 4; ks++) {
            const int d_ = 2*ks + hi;
            const short8 a0 = *(const short8*)&ktl[par][slot][l31][d_ ^ g0][0];
            const short8 a1 = *(const short8*)&ktl[par][slot][32 + l31][d_ ^ g1][0];
            s0 = __builtin_amdgcn_mfma_f32_32x32x16_bf16(a0, qf[ks], s0, 0, 0, 0);
            s1 = __builtin_amdgcn_mfma_f32_32x32x16_bf16(a1, qf[ks], s1, 0, 0, 0);
        }
        __builtin_amdgcn_s_setprio(0);

        // p = 2^s (raw v_exp_f32), per-lane rsum, pack adjacent-k pairs (1 cvt_pk each)
        unsigned p[16];
#pragma unroll
        for (int i2 = 0; i2 < 8; i2++) {
            const float a0 = EXP2(s0[2*i2]), b0 = EXP2(s0[2*i2+1]);
            const float a1 = EXP2(s1[2*i2]), b1 = EXP2(s1[2*i2+1]);
            rsum += (a0 + b0) + (a1 + b1);
            p[i2]     = pkcvt(a0, b0);
            p[8 + i2] = pkcvt(a1, b1);
        }

        // build A-fragments: one lane32-swap serves both slots of a (pa,pb) pair
        unsigned fu[4][4];
#pragma unroll
        for (int g = 0; g < 4; g++) {
            const int base = (g >> 1) * 8 + (g & 1) * 4;  // 0,4,8,12
#pragma unroll
            for (int j = 0; j < 2; j++) {
                const unsigned pa = p[base + j], pb = p[base + j + 2];
#if __has_builtin(__builtin_amdgcn_permlane32_swap)
                const uint2v sw2 = __builtin_amdgcn_permlane32_swap(pa, pb, false, false);
                fu[g][j]     = sw2[0];   // {pa.lo | pb.lo}
                fu[g][j + 2] = sw2[1];   // {pa.hi | pb.hi}
#else
                const unsigned pre = hi ? pa : pb;
                const unsigned sw = (unsigned)__shfl_xor((int)pre, 32, 64);
                fu[g][j]     = hi ? sw : pa;
                fu[g][j + 2] = hi ? pb : sw;
#endif
            }
        }

        // O += P V   (swizzled V read, same g)
        __builtin_amdgcn_s_setprio(1);
#pragma unroll
        for (int ks = 0; ks < 4; ks++) {
            union { unsigned u[4]; short8 s; } pf;
            pf.u[0] = fu[ks][0]; pf.u[1] = fu[ks][1]; pf.u[2] = fu[ks][2]; pf.u[3] = fu[ks][3];
            const int k_ = 2*ks + hi;
            const short8 v0 = *(const short8*)&vtl[par][slot][l31][k_ ^ g0][0];
            const short8 v1 = *(const short8*)&vtl[par][slot][32 + l31][k_ ^ g1][0];
            o0 = __builtin_amdgcn_mfma_f32_32x32x16_bf16(pf.s, v0, o0, 0, 0, 0);
            o1 = __builtin_amdgcn_mfma_f32_32x32x16_bf16(pf.s, v1, o1, 0, 0, 0);
        }
        __builtin_amdgcn_s_setprio(0);
    }
#undef STAGE

    // own-wave key-half combine
    rsum += __shfl_xor(rsum, 32, 64);

    // parity merge via LDS (reuse staging buffers; all compute done after barrier)
    float* mO = (float*)&ktl[0][0][0][0][0];    // [4][32][64]  (32 KB, fits ktl)
    float* rS = (float*)&vtl[0][0][0][0][0];    // [4][32]
    __syncthreads();
    if (par == 1) {
#pragma unroll
        for (int r = 0; r < 16; r++) {
            const int qr = (r & 3) + 8 * (r >> 2) + (hi ? 4 : 0);
            mO[(qg*32 + qr)*64 + l31]      = o0[r];
            mO[(qg*32 + qr)*64 + 32 + l31] = o1[r];
        }
        if (!hi) rS[qg*32 + l31] = rsum;
    }
    __syncthreads();
    if (par == 0) {
        const float inv = 1.0f / (rsum + rS[qg*32 + l31]);  // lane l: q-row l31
        const int b = bh >> 4, h = bh & 15;
#pragma unroll
        for (int r = 0; r < 16; r++) {
            const int qr = (r & 3) + 8 * (r >> 2) + (hi ? 4 : 0);
            const float invr = __shfl(inv, qr, 64);
            const float v0 = o0[r] + mO[(qg*32 + qr)*64 + l31];
            const float v1 = o1[r] + mO[(qg*32 + qr)*64 + 32 + l31];
            const int seq = q0 + qg*32 + qr;
            short* dst = Ob + ((size_t)(b * SEQ + seq)) * D_MODEL + h * HDIM + l31;
            dst[0]  = f2bf(v0 * invr);
            dst[32] = f2bf(v1 * invr);
        }
    }
}

// ---------------------------------------------------------------- launch
extern "C" void kernel_launch(void* const* d_in, const int* in_sizes, int n_in,
                              void* d_out, int out_size, void* d_ws, size_t ws_size,
                              hipStream_t stream)
{
    const float* x  = (const float*)d_in[0];
    const float* Wq = (const float*)d_in[1];
    const float* bq = (const float*)d_in[2];
    const float* Wk = (const float*)d_in[3];
    const float* bk = (const float*)d_in[4];
    const float* Wv = (const float*)d_in[5];
    const float* bv = (const float*)d_in[6];
    const float* Wo = (const float*)d_in[7];
    const float* bo = (const float*)d_in[8];
    float* out = (float*)d_out;

    short* ws = (short*)d_ws;
    const size_t NX = (size_t)MTOT * D_MODEL;     // 4194304
    const size_t NW = (size_t)D_MODEL * D_MODEL;  // 1048576
    short* xb  = ws;
    short* wqb = xb  + NX;
    short* wkb = wqb + NW;
    short* wvb = wkb + NW;
    short* wob = wvb + NW;
    short* Qb  = wob + NW;
    short* Kb  = Qb  + NX;
    short* Vt  = Kb  + NX;   // V stored transposed directly by qkv_gemm
    short* Ob  = Vt  + NX;

    cast_all_kernel<<<dim3(4096), 256, 0, stream>>>(x, Wq, Wk, Wv, Wo, xb, wqb, wkb, wvb, wob);
    qkv_gemm_kernel<<<dim3(8, 32, 3), 256, 0, stream>>>(xb, wqb, wkb, wvb, bq, bk, bv, Qb, Kb, Vt);
    attn_kernel<<<dim3(512), 512, 0, stream>>>(Qb, Kb, Vt, Ob);
    out_gemm_kernel<<<dim3(16, 32), 256, 0, stream>>>(Ob, wob, bo, out);
}

// Round 12
// 182.285 us; speedup vs baseline: 1.0258x; 1.0258x over previous
//
#include <hip/hip_runtime.h>
#include <cstdint>
#include <math.h>

typedef __attribute__((ext_vector_type(8))) short short8;
typedef __attribute__((ext_vector_type(4))) short shortx4;
typedef __attribute__((ext_vector_type(4))) float floatx4;
typedef __attribute__((ext_vector_type(16))) float floatx16;
typedef __attribute__((ext_vector_type(2))) unsigned uint2v;

#define D_MODEL 1024
#define NHEAD   16
#define HDIM    64
#define BATCH   2
#define SEQ     2048
#define MTOT    (BATCH*SEQ)   /* 4096 */

#if __has_builtin(__builtin_amdgcn_exp2f)
#define EXP2(x) __builtin_amdgcn_exp2f(x)
#else
#define EXP2(x) exp2f(x)
#endif

// round-to-nearest-even f32 -> bf16 (bits in a short)
__device__ __forceinline__ short f2bf(float f) {
    union { float f; uint32_t u; } v; v.f = f;
    uint32_t u = v.u;
    uint32_t r = (u + 0x7fffu + ((u >> 16) & 1u)) >> 16;
    return (short)(uint16_t)r;
}

// pack two f32 -> [bf16(lo) | bf16(hi)<<16] in ONE VALU op (T12 recipe; RNE rounding)
__device__ __forceinline__ unsigned pkcvt(float lo, float hi) {
    unsigned r;
    asm("v_cvt_pk_bf16_f32 %0, %1, %2" : "=v"(r) : "v"(lo), "v"(hi));
    return r;
}

// async global->LDS, 16B per lane. LDS dest must be wave-uniform base + lane*16.
__device__ __forceinline__ void async16(const short* g, short* l) {
    __builtin_amdgcn_global_load_lds((__attribute__((address_space(1))) void*)g,
                                     (__attribute__((address_space(3))) void*)l,
                                     16, 0, 0);
}

// ---------------------------------------------------------------- merged cast
__global__ __launch_bounds__(256) void cast_all_kernel(
    const float* __restrict__ x,  const float* __restrict__ Wq, const float* __restrict__ Wk,
    const float* __restrict__ Wv, const float* __restrict__ Wo,
    short* __restrict__ xb, short* __restrict__ wqb, short* __restrict__ wkb,
    short* __restrict__ wvb, short* __restrict__ wob)
{
    const int i = blockIdx.x * 256 + threadIdx.x;   // 8-elem group index
    const float* src; short* dst; int off;
    if (i < 524288) { src = x; dst = xb; off = i; }
    else {
        const int j = i - 524288;
        const int seg = j >> 17, o = j & 131071;
        src = (seg == 0) ? Wq : (seg == 1) ? Wk : (seg == 2) ? Wv : Wo;
        dst = (seg == 0) ? wqb : (seg == 1) ? wkb : (seg == 2) ? wvb : wob;
        off = o;
    }
    const floatx4* p = (const floatx4*)(src + (size_t)off * 8);
    floatx4 a = p[0], b = p[1];
    short8 r;
    r[0]=f2bf(a[0]); r[1]=f2bf(a[1]); r[2]=f2bf(a[2]); r[3]=f2bf(a[3]);
    r[4]=f2bf(b[0]); r[5]=f2bf(b[1]); r[6]=f2bf(b[2]); r[7]=f2bf(b[3]);
    *(short8*)(dst + (size_t)off * 8) = r;
}

// ---------------------------------------------------------------- QKV GEMM
__global__ __launch_bounds__(256, 3) void qkv_gemm_kernel(
    const short* __restrict__ Xb,
    const short* __restrict__ Wqb, const short* __restrict__ Wkb, const short* __restrict__ Wvb,
    const float* __restrict__ bq, const float* __restrict__ bk, const float* __restrict__ bv,
    short* __restrict__ Qo, short* __restrict__ Ko, short* __restrict__ Vo)
{
    const int mode = blockIdx.z;
    const short* W    = (mode == 0) ? Wqb : (mode == 1) ? Wkb : Wvb;
    const float* bias = (mode == 0) ? bq  : (mode == 1) ? bk  : bv;

    const int m_t = blockIdx.y * 128;
    const int n_t = blockIdx.x * 128;
    const int tid = threadIdx.x;
    const int lane = tid & 63, laneM = lane & 15, quad = lane >> 4;
    const int wave = tid >> 6;
    const int wm = (wave >> 1) * 64, wn = (wave & 1) * 64;

    __shared__ short la[2][128][4][8];   // [buf][row][slot][8]
    __shared__ short lb[2][128][4][8];

    floatx4 acc[4][4];
#pragma unroll
    for (int mb = 0; mb < 4; mb++)
#pragma unroll
        for (int nb = 0; nb < 4; nb++) acc[mb][nb] = (floatx4){0.f,0.f,0.f,0.f};

#define QSTAGE(bf, kk)                                                                  \
    {                                                                                   \
        int c = tid;                                                                    \
        async16(Xb + (size_t)(m_t + (c >> 2)) * D_MODEL + (kk) + ((((c & 3) ^ ((c >> 3) & 3))) * 8), \
                &la[bf][0][0][0] + c * 8);                                              \
        c = tid + 256;                                                                  \
        async16(Xb + (size_t)(m_t + (c >> 2)) * D_MODEL + (kk) + ((((c & 3) ^ ((c >> 3) & 3))) * 8), \
                &la[bf][0][0][0] + c * 8);                                              \
        c = tid;                                                                        \
        async16(W  + (size_t)(n_t + (c >> 2)) * D_MODEL + (kk) + ((((c & 3) ^ ((c >> 3) & 3))) * 8), \
                &lb[bf][0][0][0] + c * 8);                                              \
        c = tid + 256;                                                                  \
        async16(W  + (size_t)(n_t + (c >> 2)) * D_MODEL + (kk) + ((((c & 3) ^ ((c >> 3) & 3))) * 8), \
                &lb[bf][0][0][0] + c * 8);                                              \
    }

    QSTAGE(0, 0)

    const int swz = (laneM >> 1) & 3;
    for (int it = 0; it < 32; ++it) {
        const int bf = it & 1;
        __syncthreads();                       // buf[it] ready

        short8 af[4], bfv[4];
#pragma unroll
        for (int mb = 0; mb < 4; mb++) af[mb]  = *(const short8*)&la[bf][wm + mb*16 + laneM][quad ^ swz][0];
#pragma unroll
        for (int nb = 0; nb < 4; nb++) bfv[nb] = *(const short8*)&lb[bf][wn + nb*16 + laneM][quad ^ swz][0];

        if (it < 31) QSTAGE(bf ^ 1, (it + 1) * 32)

#pragma unroll
        for (int mb = 0; mb < 4; mb++)
#pragma unroll
            for (int nb = 0; nb < 4; nb++)
                acc[mb][nb] = __builtin_amdgcn_mfma_f32_16x16x32_bf16(af[mb], bfv[nb], acc[mb][nb], 0, 0, 0);
    }
#undef QSTAGE

    if (mode == 2) {
        // V: store transposed [bh][d][seq], shortx4 along seq
#pragma unroll
        for (int nb = 0; nb < 4; nb++) {
            const int col = n_t + wn + nb*16 + laneM;
            const float bb = bias[col];
            const int h = col >> 6, d = col & 63;
#pragma unroll
            for (int mb = 0; mb < 4; mb++) {
                const int row0 = m_t + wm + mb*16 + quad*4;
                const int bi = row0 >> 11, seq0 = row0 & 2047;
                shortx4 sv;
#pragma unroll
                for (int r = 0; r < 4; r++) sv[r] = f2bf(acc[mb][nb][r] + bb);
                *(shortx4*)(Vo + ((size_t)(bi*NHEAD + h) * HDIM + d) * SEQ + seq0) = sv;
            }
        }
    } else {
        short* out = (mode == 0) ? Qo : Ko;
#pragma unroll
        for (int nb = 0; nb < 4; nb++) {
            const int col = n_t + wn + nb*16 + laneM;
            const float bb = bias[col];
            const int h = col >> 6, d = col & 63;
#pragma unroll
            for (int mb = 0; mb < 4; mb++) {
                const int row0 = m_t + wm + mb*16 + quad*4;
#pragma unroll
                for (int r = 0; r < 4; r++) {
                    float v = acc[mb][nb][r] + bb;
                    v = (mode == 0) ? (2.0f*v - 1.0f) * 0.18033688011112042f  // 0.125*log2(e)
                                    : (2.0f*v - 1.0f);
                    const int m = row0 + r;
                    const int bi = m >> 11, seq = m & 2047;
                    out[((size_t)(bi*NHEAD + h) * SEQ + seq) * HDIM + d] = f2bf(v);
                }
            }
        }
    }
}

// ---------------------------------------------------------------- output GEMM
// THIS ROUND: 64x64 tile, 1024 blocks = 4 blocks/CU (vs 512 = 2/CU). Same
// staging/read template as the green kernels (invariant: read swz
// ((r&15)>>1)&3 == write fold (r>>1)&3 on bits 1-2 — holds for 64-row tiles).
// More co-resident blocks cover each other's barrier drains (inverse of R6's
// 1-block/CU regression). LDS 16KB, 256 thr, 4 waves (2x2 wave grid).
__global__ __launch_bounds__(256, 4) void out_gemm_kernel(
    const short* __restrict__ Ab, const short* __restrict__ Wb,
    const float* __restrict__ bias, float* __restrict__ out)
{
    const int m_t = blockIdx.y * 64;
    const int n_t = blockIdx.x * 64;
    const int tid = threadIdx.x;
    const int lane = tid & 63, laneM = lane & 15, quad = lane >> 4;
    const int wave = tid >> 6;
    const int wm = (wave >> 1) * 32, wn = (wave & 1) * 32;

    __shared__ short la[2][64][4][8];
    __shared__ short lb[2][64][4][8];

    floatx4 acc[2][2];
#pragma unroll
    for (int mb = 0; mb < 2; mb++)
#pragma unroll
        for (int nb = 0; nb < 2; nb++) acc[mb][nb] = (floatx4){0.f,0.f,0.f,0.f};

#define OSTAGE(bf, kk)                                                                  \
    {                                                                                   \
        const int c = tid;                                                              \
        async16(Ab + (size_t)(m_t + (c >> 2)) * D_MODEL + (kk) + ((((c & 3) ^ ((c >> 3) & 3))) * 8), \
                &la[bf][0][0][0] + c * 8);                                              \
        async16(Wb + (size_t)(n_t + (c >> 2)) * D_MODEL + (kk) + ((((c & 3) ^ ((c >> 3) & 3))) * 8), \
                &lb[bf][0][0][0] + c * 8);                                              \
    }

    OSTAGE(0, 0)

    const int swz = (laneM >> 1) & 3;
    for (int it = 0; it < 32; ++it) {
        const int bf = it & 1;
        __syncthreads();

        short8 af[2], bfv[2];
#pragma unroll
        for (int mb = 0; mb < 2; mb++) af[mb]  = *(const short8*)&la[bf][wm + mb*16 + laneM][quad ^ swz][0];
#pragma unroll
        for (int nb = 0; nb < 2; nb++) bfv[nb] = *(const short8*)&lb[bf][wn + nb*16 + laneM][quad ^ swz][0];

        if (it < 31) OSTAGE(bf ^ 1, (it + 1) * 32)

#pragma unroll
        for (int mb = 0; mb < 2; mb++)
#pragma unroll
            for (int nb = 0; nb < 2; nb++)
                acc[mb][nb] = __builtin_amdgcn_mfma_f32_16x16x32_bf16(af[mb], bfv[nb], acc[mb][nb], 0, 0, 0);
    }
#undef OSTAGE

#pragma unroll
    for (int nb = 0; nb < 2; nb++) {
        const int col = n_t + wn + nb*16 + laneM;
        const float bb = bias[col];
#pragma unroll
        for (int mb = 0; mb < 2; mb++) {
            const int row0 = m_t + wm + mb*16 + quad*4;
#pragma unroll
            for (int r = 0; r < 4; r++)
                out[(size_t)(row0 + r) * D_MODEL + col] = acc[mb][nb][r] + bb;
        }
    }
}

// ---------------------------------------------------------------- flash attention
// R10-GREEN VERBATIM (coalesced staging, g(row)=row&7 swizzle, 48.3us, total
// 185.4). R11's conflict-free g(row)=(row^(row>>3))&7 zeroed the 4.19M
// bank-conflict counter but was time-NEUTRAL (conflicts weren't on the
// critical path) and cost +4 VGPR + extra XORs -> reverted to R10.
__global__ __launch_bounds__(512, 4) void attn_kernel(const short* __restrict__ Qb,
                                                      const short* __restrict__ Kb,
                                                      const short* __restrict__ Vt,
                                                      short* __restrict__ Ob)
{
    const int bh = blockIdx.x & 31;
    const int qi = blockIdx.x >> 5;
    const int q0 = qi * 128;
    const int po = (qi & 3) * 4;                // phase stagger
    const int tid = threadIdx.x;
    const int wave = tid >> 6, lane = tid & 63;
    const int l31 = lane & 31;
    const bool hi = (lane >> 5) != 0;
    const int qg = wave & 3, par = wave >> 2;

    // K tile: [par][slot][key 64][d-octet 8][8]  (row-major key x d, swizzled oct)
    // V tile: [par][slot][d 64][key-octet 8][8]  (row-major d x key, swizzled koct)
    __shared__ short ktl[2][2][64][8][8];   // 32 KB
    __shared__ short vtl[2][2][64][8][8];   // 32 KB

    const short* Kbase = Kb + (size_t)bh * SEQ * HDIM;
    const short* Vbase = Vt + (size_t)bh * HDIM * SEQ;

    // Q fragments (MFMA B operand: B[k=d][n=q], lane n = q)
    const short* Qp = Qb + ((size_t)bh * SEQ + q0 + qg*32 + l31) * HDIM + (hi ? 8 : 0);
    short8 qf[4];
#pragma unroll
    for (int ks = 0; ks < 4; ks++) qf[ks] = *(const short8*)(Qp + ks*16);

    floatx16 o0, o1;
#pragma unroll
    for (int r = 0; r < 16; r++) { o0[r] = 0.f; o1[r] = 0.f; }
    float rsum = 0.f;

    // Coalesced stage: c = tid; row = c>>3 (key for K, d for V), oct = c&7.
    // 8 consecutive lanes cover one full 128B row. LDS slot (row, oct) receives
    // source octet soct = oct ^ (row&7)  (inverse swizzle on the global address).
#define STAGE(slot, kk)                                                                   \
    {                                                                                     \
        const int c = tid;                                                                \
        const int row_ = c >> 3, soct_ = (c & 7) ^ (row_ & 7);                            \
        async16(Kbase + (size_t)((kk) + row_) * HDIM + soct_ * 8,                         \
                &ktl[0][slot][0][0][0] + c * 8);                                          \
        async16(Kbase + (size_t)((kk) + 64 + row_) * HDIM + soct_ * 8,                    \
                &ktl[1][slot][0][0][0] + c * 8);                                          \
        async16(Vbase + (size_t)row_ * SEQ + (kk) + soct_ * 8,                            \
                &vtl[0][slot][0][0][0] + c * 8);                                          \
        async16(Vbase + (size_t)row_ * SEQ + (kk) + 64 + soct_ * 8,                       \
                &vtl[1][slot][0][0][0] + c * 8);                                          \
    }

    STAGE(0, po * 128)

    for (int i = 0; i < 16; ++i) {
        const int slot = i & 1;
        __syncthreads();                        // both parity tiles of phase i ready
        if (i < 15) STAGE(slot ^ 1, (((i + 1 + po) & 15)) * 128)

        // S^T: D[m=key][n=q]   (swizzled read: oct ^ (row&7); (32+l31)&7 == l31&7)
        floatx16 s0, s1;
#pragma unroll
        for (int r = 0; r < 16; r++) { s0[r] = 0.f; s1[r] = 0.f; }
        __builtin_amdgcn_s_setprio(1);
#pragma unroll
        for (int ks = 0; ks < 4; ks++) {
            const int oct = (2*ks + hi) ^ (l31 & 7);
            const short8 a0 = *(const short8*)&ktl[par][slot][l31][oct][0];
            const short8 a1 = *(const short8*)&ktl[par][slot][32 + l31][oct][0];
            s0 = __builtin_amdgcn_mfma_f32_32x32x16_bf16(a0, qf[ks], s0, 0, 0, 0);
            s1 = __builtin_amdgcn_mfma_f32_32x32x16_bf16(a1, qf[ks], s1, 0, 0, 0);
        }
        __builtin_amdgcn_s_setprio(0);

        // p = 2^s (raw v_exp_f32), per-lane rsum, pack adjacent-k pairs (1 cvt_pk each)
        unsigned p[16];
#pragma unroll
        for (int i2 = 0; i2 < 8; i2++) {
            const float a0 = EXP2(s0[2*i2]), b0 = EXP2(s0[2*i2+1]);
            const float a1 = EXP2(s1[2*i2]), b1 = EXP2(s1[2*i2+1]);
            rsum += (a0 + b0) + (a1 + b1);
            p[i2]     = pkcvt(a0, b0);
            p[8 + i2] = pkcvt(a1, b1);
        }

        // build A-fragments: one lane32-swap serves both slots of a (pa,pb) pair
        unsigned fu[4][4];
#pragma unroll
        for (int g = 0; g < 4; g++) {
            const int base = (g >> 1) * 8 + (g & 1) * 4;  // 0,4,8,12
#pragma unroll
            for (int j = 0; j < 2; j++) {
                const unsigned pa = p[base + j], pb = p[base + j + 2];
#if __has_builtin(__builtin_amdgcn_permlane32_swap)
                const uint2v sw2 = __builtin_amdgcn_permlane32_swap(pa, pb, false, false);
                fu[g][j]     = sw2[0];   // {pa.lo | pb.lo}
                fu[g][j + 2] = sw2[1];   // {pa.hi | pb.hi}
#else
                const unsigned pre = hi ? pa : pb;
                const unsigned sw = (unsigned)__shfl_xor((int)pre, 32, 64);
                fu[g][j]     = hi ? sw : pa;
                fu[g][j + 2] = hi ? pb : sw;
#endif
            }
        }

        // O += P V   (swizzled V read, same XOR)
        __builtin_amdgcn_s_setprio(1);
#pragma unroll
        for (int ks = 0; ks < 4; ks++) {
            union { unsigned u[4]; short8 s; } pf;
            pf.u[0] = fu[ks][0]; pf.u[1] = fu[ks][1]; pf.u[2] = fu[ks][2]; pf.u[3] = fu[ks][3];
            const int koct = (2*ks + hi) ^ (l31 & 7);
            const short8 v0 = *(const short8*)&vtl[par][slot][l31][koct][0];
            const short8 v1 = *(const short8*)&vtl[par][slot][32 + l31][koct][0];
            o0 = __builtin_amdgcn_mfma_f32_32x32x16_bf16(pf.s, v0, o0, 0, 0, 0);
            o1 = __builtin_amdgcn_mfma_f32_32x32x16_bf16(pf.s, v1, o1, 0, 0, 0);
        }
        __builtin_amdgcn_s_setprio(0);
    }
#undef STAGE

    // own-wave key-half combine
    rsum += __shfl_xor(rsum, 32, 64);

    // parity merge via LDS (reuse staging buffers; all compute done after barrier)
    float* mO = (float*)&ktl[0][0][0][0][0];    // [4][32][64]  (32 KB, fits ktl)
    float* rS = (float*)&vtl[0][0][0][0][0];    // [4][32]
    __syncthreads();
    if (par == 1) {
#pragma unroll
        for (int r = 0; r < 16; r++) {
            const int qr = (r & 3) + 8 * (r >> 2) + (hi ? 4 : 0);
            mO[(qg*32 + qr)*64 + l31]      = o0[r];
            mO[(qg*32 + qr)*64 + 32 + l31] = o1[r];
        }
        if (!hi) rS[qg*32 + l31] = rsum;
    }
    __syncthreads();
    if (par == 0) {
        const float inv = 1.0f / (rsum + rS[qg*32 + l31]);  // lane l: q-row l31
        const int b = bh >> 4, h = bh & 15;
#pragma unroll
        for (int r = 0; r < 16; r++) {
            const int qr = (r & 3) + 8 * (r >> 2) + (hi ? 4 : 0);
            const float invr = __shfl(inv, qr, 64);
            const float v0 = o0[r] + mO[(qg*32 + qr)*64 + l31];
            const float v1 = o1[r] + mO[(qg*32 + qr)*64 + 32 + l31];
            const int seq = q0 + qg*32 + qr;
            short* dst = Ob + ((size_t)(b * SEQ + seq)) * D_MODEL + h * HDIM + l31;
            dst[0]  = f2bf(v0 * invr);
            dst[32] = f2bf(v1 * invr);
        }
    }
}

// ---------------------------------------------------------------- launch
extern "C" void kernel_launch(void* const* d_in, const int* in_sizes, int n_in,
                              void* d_out, int out_size, void* d_ws, size_t ws_size,
                              hipStream_t stream)
{
    const float* x  = (const float*)d_in[0];
    const float* Wq = (const float*)d_in[1];
    const float* bq = (const float*)d_in[2];
    const float* Wk = (const float*)d_in[3];
    const float* bk = (const float*)d_in[4];
    const float* Wv = (const float*)d_in[5];
    const float* bv = (const float*)d_in[6];
    const float* Wo = (const float*)d_in[7];
    const float* bo = (const float*)d_in[8];
    float* out = (float*)d_out;

    short* ws = (short*)d_ws;
    const size_t NX = (size_t)MTOT * D_MODEL;     // 4194304
    const size_t NW = (size_t)D_MODEL * D_MODEL;  // 1048576
    short* xb  = ws;
    short* wqb = xb  + NX;
    short* wkb = wqb + NW;
    short* wvb = wkb + NW;
    short* wob = wvb + NW;
    short* Qb  = wob + NW;
    short* Kb  = Qb  + NX;
    short* Vt  = Kb  + NX;   // V stored transposed directly by qkv_gemm
    short* Ob  = Vt  + NX;

    cast_all_kernel<<<dim3(4096), 256, 0, stream>>>(x, Wq, Wk, Wv, Wo, xb, wqb, wkb, wvb, wob);
    qkv_gemm_kernel<<<dim3(8, 32, 3), 256, 0, stream>>>(xb, wqb, wkb, wvb, bq, bk, bv, Qb, Kb, Vt);
    attn_kernel<<<dim3(512), 512, 0, stream>>>(Qb, Kb, Vt, Ob);
    out_gemm_kernel<<<dim3(16, 64), 256, 0, stream>>>(Ob, wob, bo, out);
}

// Round 14
// 181.491 us; speedup vs baseline: 1.0303x; 1.0044x over previous
//
#include <hip/hip_runtime.h>
#include <cstdint>
#include <math.h>

typedef __attribute__((ext_vector_type(8))) short short8;
typedef __attribute__((ext_vector_type(4))) short shortx4;
typedef __attribute__((ext_vector_type(4))) float floatx4;
typedef __attribute__((ext_vector_type(16))) float floatx16;
typedef __attribute__((ext_vector_type(2))) unsigned uint2v;

#define D_MODEL 1024
#define NHEAD   16
#define HDIM    64
#define BATCH   2
#define SEQ     2048
#define MTOT    (BATCH*SEQ)   /* 4096 */

#if __has_builtin(__builtin_amdgcn_exp2f)
#define EXP2(x) __builtin_amdgcn_exp2f(x)
#else
#define EXP2(x) exp2f(x)
#endif

// round-to-nearest-even f32 -> bf16 (bits in a short)
__device__ __forceinline__ short f2bf(float f) {
    union { float f; uint32_t u; } v; v.f = f;
    uint32_t u = v.u;
    uint32_t r = (u + 0x7fffu + ((u >> 16) & 1u)) >> 16;
    return (short)(uint16_t)r;
}

// pack two f32 -> [bf16(lo) | bf16(hi)<<16] in ONE VALU op (T12 recipe; RNE rounding)
__device__ __forceinline__ unsigned pkcvt(float lo, float hi) {
    unsigned r;
    asm("v_cvt_pk_bf16_f32 %0, %1, %2" : "=v"(r) : "v"(lo), "v"(hi));
    return r;
}

// async global->LDS, 16B per lane. LDS dest must be wave-uniform base + lane*16.
__device__ __forceinline__ void async16(const short* g, short* l) {
    __builtin_amdgcn_global_load_lds((__attribute__((address_space(1))) void*)g,
                                     (__attribute__((address_space(3))) void*)l,
                                     16, 0, 0);
}

// ---------------------------------------------------------------- merged cast
__global__ __launch_bounds__(256) void cast_all_kernel(
    const float* __restrict__ x,  const float* __restrict__ Wq, const float* __restrict__ Wk,
    const float* __restrict__ Wv, const float* __restrict__ Wo,
    short* __restrict__ xb, short* __restrict__ wqb, short* __restrict__ wkb,
    short* __restrict__ wvb, short* __restrict__ wob)
{
    const int i = blockIdx.x * 256 + threadIdx.x;   // 8-elem group index
    const float* src; short* dst; int off;
    if (i < 524288) { src = x; dst = xb; off = i; }
    else {
        const int j = i - 524288;
        const int seg = j >> 17, o = j & 131071;
        src = (seg == 0) ? Wq : (seg == 1) ? Wk : (seg == 2) ? Wv : Wo;
        dst = (seg == 0) ? wqb : (seg == 1) ? wkb : (seg == 2) ? wvb : wob;
        off = o;
    }
    const floatx4* p = (const floatx4*)(src + (size_t)off * 8);
    floatx4 a = p[0], b = p[1];
    short8 r;
    r[0]=f2bf(a[0]); r[1]=f2bf(a[1]); r[2]=f2bf(a[2]); r[3]=f2bf(a[3]);
    r[4]=f2bf(b[0]); r[5]=f2bf(b[1]); r[6]=f2bf(b[2]); r[7]=f2bf(b[3]);
    *(short8*)(dst + (size_t)off * 8) = r;
}

// ---------------------------------------------------------------- QKV GEMM
__global__ __launch_bounds__(256, 3) void qkv_gemm_kernel(
    const short* __restrict__ Xb,
    const short* __restrict__ Wqb, const short* __restrict__ Wkb, const short* __restrict__ Wvb,
    const float* __restrict__ bq, const float* __restrict__ bk, const float* __restrict__ bv,
    short* __restrict__ Qo, short* __restrict__ Ko, short* __restrict__ Vo)
{
    const int mode = blockIdx.z;
    const short* W    = (mode == 0) ? Wqb : (mode == 1) ? Wkb : Wvb;
    const float* bias = (mode == 0) ? bq  : (mode == 1) ? bk  : bv;

    const int m_t = blockIdx.y * 128;
    const int n_t = blockIdx.x * 128;
    const int tid = threadIdx.x;
    const int lane = tid & 63, laneM = lane & 15, quad = lane >> 4;
    const int wave = tid >> 6;
    const int wm = (wave >> 1) * 64, wn = (wave & 1) * 64;

    __shared__ short la[2][128][4][8];   // [buf][row][slot][8]
    __shared__ short lb[2][128][4][8];

    floatx4 acc[4][4];
#pragma unroll
    for (int mb = 0; mb < 4; mb++)
#pragma unroll
        for (int nb = 0; nb < 4; nb++) acc[mb][nb] = (floatx4){0.f,0.f,0.f,0.f};

#define QSTAGE(bf, kk)                                                                  \
    {                                                                                   \
        int c = tid;                                                                    \
        async16(Xb + (size_t)(m_t + (c >> 2)) * D_MODEL + (kk) + ((((c & 3) ^ ((c >> 3) & 3))) * 8), \
                &la[bf][0][0][0] + c * 8);                                              \
        c = tid + 256;                                                                  \
        async16(Xb + (size_t)(m_t + (c >> 2)) * D_MODEL + (kk) + ((((c & 3) ^ ((c >> 3) & 3))) * 8), \
                &la[bf][0][0][0] + c * 8);                                              \
        c = tid;                                                                        \
        async16(W  + (size_t)(n_t + (c >> 2)) * D_MODEL + (kk) + ((((c & 3) ^ ((c >> 3) & 3))) * 8), \
                &lb[bf][0][0][0] + c * 8);                                              \
        c = tid + 256;                                                                  \
        async16(W  + (size_t)(n_t + (c >> 2)) * D_MODEL + (kk) + ((((c & 3) ^ ((c >> 3) & 3))) * 8), \
                &lb[bf][0][0][0] + c * 8);                                              \
    }

    QSTAGE(0, 0)

    const int swz = (laneM >> 1) & 3;
    for (int it = 0; it < 32; ++it) {
        const int bf = it & 1;
        __syncthreads();                       // buf[it] ready

        short8 af[4], bfv[4];
#pragma unroll
        for (int mb = 0; mb < 4; mb++) af[mb]  = *(const short8*)&la[bf][wm + mb*16 + laneM][quad ^ swz][0];
#pragma unroll
        for (int nb = 0; nb < 4; nb++) bfv[nb] = *(const short8*)&lb[bf][wn + nb*16 + laneM][quad ^ swz][0];

        if (it < 31) QSTAGE(bf ^ 1, (it + 1) * 32)

#pragma unroll
        for (int mb = 0; mb < 4; mb++)
#pragma unroll
            for (int nb = 0; nb < 4; nb++)
                acc[mb][nb] = __builtin_amdgcn_mfma_f32_16x16x32_bf16(af[mb], bfv[nb], acc[mb][nb], 0, 0, 0);
    }
#undef QSTAGE

    if (mode == 2) {
        // V: store transposed [bh][d][seq], shortx4 along seq
#pragma unroll
        for (int nb = 0; nb < 4; nb++) {
            const int col = n_t + wn + nb*16 + laneM;
            const float bb = bias[col];
            const int h = col >> 6, d = col & 63;
#pragma unroll
            for (int mb = 0; mb < 4; mb++) {
                const int row0 = m_t + wm + mb*16 + quad*4;
                const int bi = row0 >> 11, seq0 = row0 & 2047;
                shortx4 sv;
#pragma unroll
                for (int r = 0; r < 4; r++) sv[r] = f2bf(acc[mb][nb][r] + bb);
                *(shortx4*)(Vo + ((size_t)(bi*NHEAD + h) * HDIM + d) * SEQ + seq0) = sv;
            }
        }
    } else {
        short* out = (mode == 0) ? Qo : Ko;
#pragma unroll
        for (int nb = 0; nb < 4; nb++) {
            const int col = n_t + wn + nb*16 + laneM;
            const float bb = bias[col];
            const int h = col >> 6, d = col & 63;
#pragma unroll
            for (int mb = 0; mb < 4; mb++) {
                const int row0 = m_t + wm + mb*16 + quad*4;
#pragma unroll
                for (int r = 0; r < 4; r++) {
                    float v = acc[mb][nb][r] + bb;
                    v = (mode == 0) ? (2.0f*v - 1.0f) * 0.18033688011112042f  // 0.125*log2(e)
                                    : (2.0f*v - 1.0f);
                    const int m = row0 + r;
                    const int bi = m >> 11, seq = m & 2047;
                    out[((size_t)(bi*NHEAD + h) * SEQ + seq) * HDIM + d] = f2bf(v);
                }
            }
        }
    }
}

// ---------------------------------------------------------------- output GEMM
// R12-green 64x64 tile, 1024 blocks = 4 blocks/CU.
__global__ __launch_bounds__(256, 4) void out_gemm_kernel(
    const short* __restrict__ Ab, const short* __restrict__ Wb,
    const float* __restrict__ bias, float* __restrict__ out)
{
    const int m_t = blockIdx.y * 64;
    const int n_t = blockIdx.x * 64;
    const int tid = threadIdx.x;
    const int lane = tid & 63, laneM = lane & 15, quad = lane >> 4;
    const int wave = tid >> 6;
    const int wm = (wave >> 1) * 32, wn = (wave & 1) * 32;

    __shared__ short la[2][64][4][8];
    __shared__ short lb[2][64][4][8];

    floatx4 acc[2][2];
#pragma unroll
    for (int mb = 0; mb < 2; mb++)
#pragma unroll
        for (int nb = 0; nb < 2; nb++) acc[mb][nb] = (floatx4){0.f,0.f,0.f,0.f};

#define OSTAGE(bf, kk)                                                                  \
    {                                                                                   \
        const int c = tid;                                                              \
        async16(Ab + (size_t)(m_t + (c >> 2)) * D_MODEL + (kk) + ((((c & 3) ^ ((c >> 3) & 3))) * 8), \
                &la[bf][0][0][0] + c * 8);                                              \
        async16(Wb + (size_t)(n_t + (c >> 2)) * D_MODEL + (kk) + ((((c & 3) ^ ((c >> 3) & 3))) * 8), \
                &lb[bf][0][0][0] + c * 8);                                              \
    }

    OSTAGE(0, 0)

    const int swz = (laneM >> 1) & 3;
    for (int it = 0; it < 32; ++it) {
        const int bf = it & 1;
        __syncthreads();

        short8 af[2], bfv[2];
#pragma unroll
        for (int mb = 0; mb < 2; mb++) af[mb]  = *(const short8*)&la[bf][wm + mb*16 + laneM][quad ^ swz][0];
#pragma unroll
        for (int nb = 0; nb < 2; nb++) bfv[nb] = *(const short8*)&lb[bf][wn + nb*16 + laneM][quad ^ swz][0];

        if (it < 31) OSTAGE(bf ^ 1, (it + 1) * 32)

#pragma unroll
        for (int mb = 0; mb < 2; mb++)
#pragma unroll
            for (int nb = 0; nb < 2; nb++)
                acc[mb][nb] = __builtin_amdgcn_mfma_f32_16x16x32_bf16(af[mb], bfv[nb], acc[mb][nb], 0, 0, 0);
    }
#undef OSTAGE

#pragma unroll
    for (int nb = 0; nb < 2; nb++) {
        const int col = n_t + wn + nb*16 + laneM;
        const float bb = bias[col];
#pragma unroll
        for (int mb = 0; mb < 2; mb++) {
            const int row0 = m_t + wm + mb*16 + quad*4;
#pragma unroll
            for (int r = 0; r < 4; r++)
                out[(size_t)(row0 + r) * D_MODEL + col] = acc[mb][nb][r] + bb;
        }
    }
}

// ---------------------------------------------------------------- flash attention
// R12-GREEN VERBATIM (coalesced staging, row&7 swizzle, in-iteration
// QKT->softmax->PV, builtin permlane32_swap, T5 setprio). 48-50us.
// CLOSED INVESTIGATIONS (do not re-attempt without local disasm/repro):
//  * T15 cross-tile PV pipeline: red with BOTH opaque-asm swap (R2, 0.73) and
//    visible-builtin swap (R13, 1.18) -> asm-WAR theory refuted; intrinsic bug
//    in deferred-fu execution, undiagnosable headlessly.
//  * racc-via-MFMA: deterministic absmax 1.0657 under both swaps -> logic bug.
//  * conflict-free swizzle (R11): zeroed 4.19M conflict counter, time-neutral
//    (conflicts off critical path) -> reverted.
__global__ __launch_bounds__(512, 4) void attn_kernel(const short* __restrict__ Qb,
                                                      const short* __restrict__ Kb,
                                                      const short* __restrict__ Vt,
                                                      short* __restrict__ Ob)
{
    const int bh = blockIdx.x & 31;
    const int qi = blockIdx.x >> 5;
    const int q0 = qi * 128;
    const int po = (qi & 3) * 4;                // phase stagger
    const int tid = threadIdx.x;
    const int wave = tid >> 6, lane = tid & 63;
    const int l31 = lane & 31;
    const bool hi = (lane >> 5) != 0;
    const int qg = wave & 3, par = wave >> 2;

    // K tile: [par][slot][key 64][d-octet 8][8]  (row-major key x d, swizzled oct)
    // V tile: [par][slot][d 64][key-octet 8][8]  (row-major d x key, swizzled koct)
    __shared__ short ktl[2][2][64][8][8];   // 32 KB
    __shared__ short vtl[2][2][64][8][8];   // 32 KB

    const short* Kbase = Kb + (size_t)bh * SEQ * HDIM;
    const short* Vbase = Vt + (size_t)bh * HDIM * SEQ;

    // Q fragments (MFMA B operand: B[k=d][n=q], lane n = q)
    const short* Qp = Qb + ((size_t)bh * SEQ + q0 + qg*32 + l31) * HDIM + (hi ? 8 : 0);
    short8 qf[4];
#pragma unroll
    for (int ks = 0; ks < 4; ks++) qf[ks] = *(const short8*)(Qp + ks*16);

    floatx16 o0, o1;
#pragma unroll
    for (int r = 0; r < 16; r++) { o0[r] = 0.f; o1[r] = 0.f; }
    float rsum = 0.f;

    // Coalesced stage: c = tid; row = c>>3 (key for K, d for V), oct = c&7.
    // 8 consecutive lanes cover one full 128B row. LDS slot (row, oct) receives
    // source octet soct = oct ^ (row&7)  (inverse swizzle on the global address).
#define STAGE(slot, kk)                                                                   \
    {                                                                                     \
        const int c = tid;                                                                \
        const int row_ = c >> 3, soct_ = (c & 7) ^ (row_ & 7);                            \
        async16(Kbase + (size_t)((kk) + row_) * HDIM + soct_ * 8,                         \
                &ktl[0][slot][0][0][0] + c * 8);                                          \
        async16(Kbase + (size_t)((kk) + 64 + row_) * HDIM + soct_ * 8,                    \
                &ktl[1][slot][0][0][0] + c * 8);                                          \
        async16(Vbase + (size_t)row_ * SEQ + (kk) + soct_ * 8,                            \
                &vtl[0][slot][0][0][0] + c * 8);                                          \
        async16(Vbase + (size_t)row_ * SEQ + (kk) + 64 + soct_ * 8,                       \
                &vtl[1][slot][0][0][0] + c * 8);                                          \
    }

    STAGE(0, po * 128)

    for (int i = 0; i < 16; ++i) {
        const int slot = i & 1;
        __syncthreads();                        // both parity tiles of phase i ready
        if (i < 15) STAGE(slot ^ 1, (((i + 1 + po) & 15)) * 128)

        // S^T: D[m=key][n=q]   (swizzled read: oct ^ (row&7); (32+l31)&7 == l31&7)
        floatx16 s0, s1;
#pragma unroll
        for (int r = 0; r < 16; r++) { s0[r] = 0.f; s1[r] = 0.f; }
        __builtin_amdgcn_s_setprio(1);
#pragma unroll
        for (int ks = 0; ks < 4; ks++) {
            const int oct = (2*ks + hi) ^ (l31 & 7);
            const short8 a0 = *(const short8*)&ktl[par][slot][l31][oct][0];
            const short8 a1 = *(const short8*)&ktl[par][slot][32 + l31][oct][0];
            s0 = __builtin_amdgcn_mfma_f32_32x32x16_bf16(a0, qf[ks], s0, 0, 0, 0);
            s1 = __builtin_amdgcn_mfma_f32_32x32x16_bf16(a1, qf[ks], s1, 0, 0, 0);
        }
        __builtin_amdgcn_s_setprio(0);

        // p = 2^s (raw v_exp_f32), per-lane rsum, pack adjacent-k pairs (1 cvt_pk each)
        unsigned p[16];
#pragma unroll
        for (int i2 = 0; i2 < 8; i2++) {
            const float a0 = EXP2(s0[2*i2]), b0 = EXP2(s0[2*i2+1]);
            const float a1 = EXP2(s1[2*i2]), b1 = EXP2(s1[2*i2+1]);
            rsum += (a0 + b0) + (a1 + b1);
            p[i2]     = pkcvt(a0, b0);
            p[8 + i2] = pkcvt(a1, b1);
        }

        // build A-fragments: one lane32-swap serves both slots of a (pa,pb) pair
        unsigned fu[4][4];
#pragma unroll
        for (int g = 0; g < 4; g++) {
            const int base = (g >> 1) * 8 + (g & 1) * 4;  // 0,4,8,12
#pragma unroll
            for (int j = 0; j < 2; j++) {
                const unsigned pa = p[base + j], pb = p[base + j + 2];
#if __has_builtin(__builtin_amdgcn_permlane32_swap)
                const uint2v sw2 = __builtin_amdgcn_permlane32_swap(pa, pb, false, false);
                fu[g][j]     = sw2[0];   // {pa.lo | pb.lo}
                fu[g][j + 2] = sw2[1];   // {pa.hi | pb.hi}
#else
                const unsigned pre = hi ? pa : pb;
                const unsigned sw = (unsigned)__shfl_xor((int)pre, 32, 64);
                fu[g][j]     = hi ? sw : pa;
                fu[g][j + 2] = hi ? pb : sw;
#endif
            }
        }

        // O += P V   (swizzled V read, same XOR)
        __builtin_amdgcn_s_setprio(1);
#pragma unroll
        for (int ks = 0; ks < 4; ks++) {
            union { unsigned u[4]; short8 s; } pf;
            pf.u[0] = fu[ks][0]; pf.u[1] = fu[ks][1]; pf.u[2] = fu[ks][2]; pf.u[3] = fu[ks][3];
            const int koct = (2*ks + hi) ^ (l31 & 7);
            const short8 v0 = *(const short8*)&vtl[par][slot][l31][koct][0];
            const short8 v1 = *(const short8*)&vtl[par][slot][32 + l31][koct][0];
            o0 = __builtin_amdgcn_mfma_f32_32x32x16_bf16(pf.s, v0, o0, 0, 0, 0);
            o1 = __builtin_amdgcn_mfma_f32_32x32x16_bf16(pf.s, v1, o1, 0, 0, 0);
        }
        __builtin_amdgcn_s_setprio(0);
    }
#undef STAGE

    // own-wave key-half combine
    rsum += __shfl_xor(rsum, 32, 64);

    // parity merge via LDS (reuse staging buffers; all compute done after barrier)
    float* mO = (float*)&ktl[0][0][0][0][0];    // [4][32][64]  (32 KB, fits ktl)
    float* rS = (float*)&vtl[0][0][0][0][0];    // [4][32]
    __syncthreads();
    if (par == 1) {
#pragma unroll
        for (int r = 0; r < 16; r++) {
            const int qr = (r & 3) + 8 * (r >> 2) + (hi ? 4 : 0);
            mO[(qg*32 + qr)*64 + l31]      = o0[r];
            mO[(qg*32 + qr)*64 + 32 + l31] = o1[r];
        }
        if (!hi) rS[qg*32 + l31] = rsum;
    }
    __syncthreads();
    if (par == 0) {
        const float inv = 1.0f / (rsum + rS[qg*32 + l31]);  // lane l: q-row l31
        const int b = bh >> 4, h = bh & 15;
#pragma unroll
        for (int r = 0; r < 16; r++) {
            const int qr = (r & 3) + 8 * (r >> 2) + (hi ? 4 : 0);
            const float invr = __shfl(inv, qr, 64);
            const float v0 = o0[r] + mO[(qg*32 + qr)*64 + l31];
            const float v1 = o1[r] + mO[(qg*32 + qr)*64 + 32 + l31];
            const int seq = q0 + qg*32 + qr;
            short* dst = Ob + ((size_t)(b * SEQ + seq)) * D_MODEL + h * HDIM + l31;
            dst[0]  = f2bf(v0 * invr);
            dst[32] = f2bf(v1 * invr);
        }
    }
}

// ---------------------------------------------------------------- launch
extern "C" void kernel_launch(void* const* d_in, const int* in_sizes, int n_in,
                              void* d_out, int out_size, void* d_ws, size_t ws_size,
                              hipStream_t stream)
{
    const float* x  = (const float*)d_in[0];
    const float* Wq = (const float*)d_in[1];
    const float* bq = (const float*)d_in[2];
    const float* Wk = (const float*)d_in[3];
    const float* bk = (const float*)d_in[4];
    const float* Wv = (const float*)d_in[5];
    const float* bv = (const float*)d_in[6];
    const float* Wo = (const float*)d_in[7];
    const float* bo = (const float*)d_in[8];
    float* out = (float*)d_out;

    short* ws = (short*)d_ws;
    const size_t NX = (size_t)MTOT * D_MODEL;     // 4194304
    const size_t NW = (size_t)D_MODEL * D_MODEL;  // 1048576
    short* xb  = ws;
    short* wqb = xb  + NX;
    short* wkb = wqb + NW;
    short* wvb = wkb + NW;
    short* wob = wvb + NW;
    short* Qb  = wob + NW;
    short* Kb  = Qb  + NX;
    short* Vt  = Kb  + NX;   // V stored transposed directly by qkv_gemm
    short* Ob  = Vt  + NX;

    cast_all_kernel<<<dim3(4096), 256, 0, stream>>>(x, Wq, Wk, Wv, Wo, xb, wqb, wkb, wvb, wob);
    qkv_gemm_kernel<<<dim3(8, 32, 3), 256, 0, stream>>>(xb, wqb, wkb, wvb, bq, bk, bv, Qb, Kb, Vt);
    attn_kernel<<<dim3(512), 512, 0, stream>>>(Qb, Kb, Vt, Ob);
    out_gemm_kernel<<<dim3(16, 64), 256, 0, stream>>>(Ob, wob, bo, out);
}